// Round 9
// baseline (38.589 us; speedup 1.0000x reference)
//
#include <hip/hip_runtime.h>

#define BB 16
#define NN 6000
#define GG 512
#define WAVES 8
#define RPB 128   // ROIs per block (2 per lane)

__device__ __forceinline__ float rl_f(float v, int i) {
    return __int_as_float(__builtin_amdgcn_readlane(__float_as_int(v), i));
}

__global__ __launch_bounds__(64 * WAVES) void det_kernel(
    const float4* __restrict__ rois,      // (B, N, 4)
    const int*    __restrict__ gt_ids,    // (B, G)
    const float4* __restrict__ gt_boxes,  // (B, G, 4)
    float*        __restrict__ out)       // [B*2*N maxes][B*N pos][B*N neg]
{
    __shared__ float s_ncm[WAVES][RPB];
    __shared__ float s_cm[WAVES][RPB];
    __shared__ float s_val[RPB];

    const int b    = blockIdx.y;
    const int tid  = threadIdx.x;
    const int wave = tid >> 6;
    const int lane = tid & 63;

    // Each wave owns GTs [wave*64, wave*64+64); lane holds one GT in registers.
    const int g = wave * 64 + lane;
    const float4 gbx   = gt_boxes[b * GG + g];
    const float  garea = (gbx.z - gbx.x) * (gbx.w - gbx.y);
    const int    gident = gt_ids[b * GG + g];

    // Two ROIs per lane (slots lane and 64+lane) — same ROIs for all waves.
    const int nbase = blockIdx.x * RPB;
    const int n0 = nbase + lane;
    const int n1 = nbase + 64 + lane;
    const float4 z4 = make_float4(0.f, 0.f, 0.f, 0.f);
    const float4 r0 = (n0 < NN) ? rois[b * NN + n0] : z4;
    const float4 r1 = (n1 < NN) ? rois[b * NN + n1] : z4;
    const bool  v0 = (fabsf(r0.x) + fabsf(r0.y) + fabsf(r0.z) + fabsf(r0.w)) > 0.0f;
    const bool  v1 = (fabsf(r1.x) + fabsf(r1.y) + fabsf(r1.z) + fabsf(r1.w)) > 0.0f;
    const float rs0 = (r0.z - r0.x) * (r0.w - r0.y) + 1e-8f;
    const float rs1 = (r1.z - r1.x) * (r1.w - r1.y) + 1e-8f;

    if (wave == 0) {
        s_val[lane]      = v0 ? 1.0f : 0.0f;
        s_val[64 + lane] = v1 ? 1.0f : 0.0f;
    }

    float nc0 = 0.f, nc1 = 0.f, c0 = 0.f, c1 = 0.f;

    // Hot loop: broadcast GT i from lane i's registers (pure VALU, no memory).
    #pragma unroll 4
    for (int i = 0; i < 64; ++i) {
        const int   sid = __builtin_amdgcn_readlane(gident, i);
        const float gy1 = rl_f(gbx.x, i);
        const float gx1 = rl_f(gbx.y, i);
        const float gy2 = rl_f(gbx.z, i);
        const float gx2 = rl_f(gbx.w, i);
        const float ga  = rl_f(garea, i);
        const float fn  = (sid > 0) ? 1.0f : 0.0f;   // uniform -> s_cselect
        const float fc  = (sid < 0) ? 1.0f : 0.0f;
        {   // ROI 0
            float yy1 = fmaxf(r0.x, gy1);
            float xx1 = fmaxf(r0.y, gx1);
            float yy2 = fminf(r0.z, gy2);
            float xx2 = fminf(r0.w, gx2);
            float inter = fmaxf(yy2 - yy1, 0.f) * fmaxf(xx2 - xx1, 0.f);
            float iou = inter * __builtin_amdgcn_rcpf(rs0 + ga - inter);
            nc0 = fmaxf(nc0, iou * fn);
            c0  = fmaxf(c0,  iou * fc);
        }
        {   // ROI 1
            float yy1 = fmaxf(r1.x, gy1);
            float xx1 = fmaxf(r1.y, gx1);
            float yy2 = fminf(r1.z, gy2);
            float xx2 = fminf(r1.w, gx2);
            float inter = fmaxf(yy2 - yy1, 0.f) * fmaxf(xx2 - xx1, 0.f);
            float iou = inter * __builtin_amdgcn_rcpf(rs1 + ga - inter);
            nc1 = fmaxf(nc1, iou * fn);
            c1  = fmaxf(c1,  iou * fc);
        }
    }

    s_ncm[wave][lane]      = nc0;
    s_ncm[wave][64 + lane] = nc1;
    s_cm[wave][lane]       = c0;
    s_cm[wave][64 + lane]  = c1;
    __syncthreads();

    // Reduce across the 8 waves' GT slices; threads 0..127 each own one ROI slot.
    if (tid < RPB) {
        const int n = nbase + tid;
        if (n < NN) {
            float a = s_ncm[0][tid], c = s_cm[0][tid];
            #pragma unroll
            for (int w = 1; w < WAVES; ++w) {
                a = fmaxf(a, s_ncm[w][tid]);
                c = fmaxf(c, s_cm[w][tid]);
            }
            const float vr = s_val[tid];           // 1.0 or 0.0
            const float nc_max = a * vr;
            const float c_max  = c * vr;

            out[b * 2 * NN + n]      = nc_max;     // iou_maxes (B,2,N) ch0
            out[b * 2 * NN + NN + n] = c_max;      // iou_maxes (B,2,N) ch1
            const float pos = (vr > 0.f && nc_max >= 0.5f) ? 1.0f : 0.0f;
            const float neg = (vr > 0.f && nc_max < 0.5f && c_max < 0.001f) ? 1.0f : 0.0f;
            out[BB * 2 * NN + b * NN + n]           = pos;
            out[BB * 2 * NN + BB * NN + b * NN + n] = neg;
        }
    }
}

extern "C" void kernel_launch(void* const* d_in, const int* in_sizes, int n_in,
                              void* d_out, int out_size, void* d_ws, size_t ws_size,
                              hipStream_t stream) {
    const float4* rois     = (const float4*)d_in[0];
    const int*    gt_ids   = (const int*)d_in[1];
    const float4* gt_boxes = (const float4*)d_in[2];
    float*        out      = (float*)d_out;

    dim3 grid((NN + RPB - 1) / RPB, BB);   // 47 x 16 = 752 blocks, 8 waves each
    det_kernel<<<grid, 64 * WAVES, 0, stream>>>(rois, gt_ids, gt_boxes, out);
}

// Round 10
// 26.069 us; speedup vs baseline: 1.4803x; 1.4803x over previous
//
#include <hip/hip_runtime.h>

#define BB 16
#define NN 6000
#define GG 512
#define WAVES 8
#define RPT 3
#define RPB (RPT * 64)   // 192 ROIs per block; grid.x = 32 -> 512 blocks = 2/CU

__global__ __launch_bounds__(64 * WAVES) void det_kernel(
    const float4* __restrict__ rois,      // (B, N, 4)
    const int*    __restrict__ gt_ids,    // (B, G)
    const float4* __restrict__ gt_boxes,  // (B, G, 4)
    float*        __restrict__ out)       // [B*2*N maxes][B*N pos][B*N neg]
{
    __shared__ float4 s_box[GG];             // nc from front, crowd from back
    __shared__ float4 s_area4[GG / 4];
    __shared__ float  s_ncm[WAVES][RPB];
    __shared__ float  s_cm[WAVES][RPB];
    __shared__ float  s_val[RPB];
    __shared__ int    s_cnt[2];
    __shared__ int    s_bounds[2];
    float* s_area = (float*)s_area4;

    const int b    = blockIdx.y;
    const int tid  = threadIdx.x;
    const int wave = tid >> 6;
    const int lane = tid & 63;

    if (tid == 0) { s_cnt[0] = 0; s_cnt[1] = 0; }
    __syncthreads();

    // ---- ballot compaction: one GT per thread (512 threads == GG) ----
    {
        const int g = tid;
        float4 box = gt_boxes[b * GG + g];
        float asum = fabsf(box.x) + fabsf(box.y) + fabsf(box.z) + fabsf(box.w);
        int id = gt_ids[b * GG + g];
        const bool pn = (asum > 0.0f) && (id > 0);
        const bool pc = (asum > 0.0f) && (id < 0);
        unsigned long long mn = __ballot(pn);
        unsigned long long mc = __ballot(pc);
        int bn = 0, bc = 0;
        if (lane == 0) {
            bn = atomicAdd(&s_cnt[0], __popcll(mn));
            bc = atomicAdd(&s_cnt[1], __popcll(mc));
        }
        bn = __shfl(bn, 0);
        bc = __shfl(bc, 0);
        const unsigned long long lt = (1ULL << lane) - 1ULL;
        if (pn) {
            int idx = bn + __popcll(mn & lt);
            s_box[idx]  = box;
            s_area[idx] = (box.z - box.x) * (box.w - box.y);
        }
        if (pc) {
            int idx = (GG - 1) - (bc + __popcll(mc & lt));
            s_box[idx]  = box;
            s_area[idx] = (box.z - box.x) * (box.w - box.y);
        }
    }
    __syncthreads();

    if (tid == 0) {
        int ncnt = s_cnt[0];
        int lo   = GG - s_cnt[1];
        int nc_eff = (ncnt + 3) & ~3;   // pad nc list up to x4
        int lo_pad = lo & ~3;           // pad crowd list down to x4
        if (nc_eff > lo_pad) nc_eff = lo_pad;
        s_bounds[0] = nc_eff;
        s_bounds[1] = lo_pad;
    }
    __syncthreads();

    const int nc_eff = s_bounds[0];
    const int lo_pad = s_bounds[1];

    // zero-fill pad slots (zero box => t=0, harmless for max)
    {
        const float4 z = make_float4(0.f, 0.f, 0.f, 0.f);
        const int ncnt = s_cnt[0];
        const int lo   = GG - s_cnt[1];
        if (tid < 4) {
            int i = ncnt + tid;
            if (i < nc_eff) { s_box[i] = z; s_area[i] = 0.f; }
        } else if (tid < 8) {
            int i = lo_pad + (tid - 4);
            if (i < lo) { s_box[i] = z; s_area[i] = 0.f; }
        }
    }
    __syncthreads();

    // ---- per-thread ROIs: slots lane, 64+lane, 128+lane ----
    const int nbase = blockIdx.x * RPB;
    float4 r[RPT];
    float  rs[RPT];   // rarea + eps
    #pragma unroll
    for (int i = 0; i < RPT; ++i) {
        int n = nbase + i * 64 + lane;
        float4 rr = (n < NN) ? rois[b * NN + n] : make_float4(0.f, 0.f, 0.f, 0.f);
        r[i]  = rr;
        rs[i] = (rr.z - rr.x) * (rr.w - rr.y) + 1e-8f;
        if (wave == 0)
            s_val[i * 64 + lane] =
                ((fabsf(rr.x) + fabsf(rr.y) + fabsf(rr.z) + fabsf(rr.w)) > 0.f) ? 1.f : 0.f;
    }

    // t = inter * rcp(rarea + garea + eps)  (monotone in IoU; 13 VALU/pair)
    auto tval = [](const float4& rr, float rsum, const float4& g4, float ga) -> float {
        float dy = fminf(rr.z, g4.z) - fmaxf(rr.x, g4.x);
        float dx = fminf(rr.w, g4.w) - fmaxf(rr.y, g4.y);
        float inter = fmaxf(fmaxf(dy, 0.f) * dx, 0.f);
        return inter * __builtin_amdgcn_rcpf(rsum + ga);
    };

    float anc[RPT] = {0.f, 0.f, 0.f};
    float ac[RPT]  = {0.f, 0.f, 0.f};

    // ---- non-crowd: groups [0, nc_eff/4), split across 8 waves ----
    {
        const int ngr = nc_eff >> 2;
        const int gpw = (ngr + WAVES - 1) / WAVES;
        const int q0 = wave * gpw;
        const int q1 = min(ngr, q0 + gpw);
        for (int q = q0; q < q1; ++q) {
            float4 b0 = s_box[4 * q + 0];
            float4 b1 = s_box[4 * q + 1];
            float4 b2 = s_box[4 * q + 2];
            float4 b3 = s_box[4 * q + 3];
            float4 a4 = s_area4[q];
            #pragma unroll
            for (int i = 0; i < RPT; ++i) {
                float t0 = tval(r[i], rs[i], b0, a4.x);
                float t1 = tval(r[i], rs[i], b1, a4.y);
                float t2 = tval(r[i], rs[i], b2, a4.z);
                float t3 = tval(r[i], rs[i], b3, a4.w);
                anc[i] = fmaxf(anc[i], fmaxf(fmaxf(t0, t1), fmaxf(t2, t3)));
            }
        }
    }
    // ---- crowd: groups [lo_pad/4, GG/4), split across 8 waves ----
    {
        const int cg0 = lo_pad >> 2;
        const int cgn = (GG >> 2) - cg0;
        const int gpw = (cgn + WAVES - 1) / WAVES;
        const int q0 = cg0 + wave * gpw;
        const int q1 = min(GG >> 2, q0 + gpw);
        for (int q = q0; q < q1; ++q) {
            float4 b0 = s_box[4 * q + 0];
            float4 b1 = s_box[4 * q + 1];
            float4 b2 = s_box[4 * q + 2];
            float4 b3 = s_box[4 * q + 3];
            float4 a4 = s_area4[q];
            #pragma unroll
            for (int i = 0; i < RPT; ++i) {
                float t0 = tval(r[i], rs[i], b0, a4.x);
                float t1 = tval(r[i], rs[i], b1, a4.y);
                float t2 = tval(r[i], rs[i], b2, a4.z);
                float t3 = tval(r[i], rs[i], b3, a4.w);
                ac[i] = fmaxf(ac[i], fmaxf(fmaxf(t0, t1), fmaxf(t2, t3)));
            }
        }
    }

    #pragma unroll
    for (int i = 0; i < RPT; ++i) {
        s_ncm[wave][i * 64 + lane] = anc[i];
        s_cm[wave][i * 64 + lane]  = ac[i];
    }
    __syncthreads();

    // ---- reduce across waves; threads 0..RPB-1 own one ROI slot each ----
    if (tid < RPB) {
        const int n = nbase + tid;
        if (n < NN) {
            float a = s_ncm[0][tid], c = s_cm[0][tid];
            #pragma unroll
            for (int w = 1; w < WAVES; ++w) {
                a = fmaxf(a, s_ncm[w][tid]);
                c = fmaxf(c, s_cm[w][tid]);
            }
            const float vr = s_val[tid];           // 1.0 or 0.0
            a *= vr;
            c *= vr;
            // t -> iou: iou = t/(1-t); t in [0, 0.5] so well-conditioned
            const float nc_max = a * __builtin_amdgcn_rcpf(1.f - a);
            const float c_max  = c * __builtin_amdgcn_rcpf(1.f - c);

            out[b * 2 * NN + n]      = nc_max;     // iou_maxes (B,2,N) ch0
            out[b * 2 * NN + NN + n] = c_max;      // iou_maxes (B,2,N) ch1
            const float pos = (vr > 0.f && nc_max >= 0.5f) ? 1.0f : 0.0f;
            const float neg = (vr > 0.f && nc_max < 0.5f && c_max < 0.001f) ? 1.0f : 0.0f;
            out[BB * 2 * NN + b * NN + n]           = pos;
            out[BB * 2 * NN + BB * NN + b * NN + n] = neg;
        }
    }
}

extern "C" void kernel_launch(void* const* d_in, const int* in_sizes, int n_in,
                              void* d_out, int out_size, void* d_ws, size_t ws_size,
                              hipStream_t stream) {
    const float4* rois     = (const float4*)d_in[0];
    const int*    gt_ids   = (const int*)d_in[1];
    const float4* gt_boxes = (const float4*)d_in[2];
    float*        out      = (float*)d_out;

    dim3 grid((NN + RPB - 1) / RPB, BB);   // 32 x 16 = 512 blocks = exactly 2/CU
    det_kernel<<<grid, 64 * WAVES, 0, stream>>>(rois, gt_ids, gt_boxes, out);
}

// Round 11
// 23.791 us; speedup vs baseline: 1.6219x; 1.0957x over previous
//
#include <hip/hip_runtime.h>

#define BB 16
#define NN 6000
#define GG 512
#define WAVES 8
#define RPT 3
#define RPB (RPT * 64)   // 192 ROIs per block; grid.x = 32 -> 512 blocks = 2/CU

__global__ __launch_bounds__(64 * WAVES) void det_kernel(
    const float4* __restrict__ rois,      // (B, N, 4)
    const int*    __restrict__ gt_ids,    // (B, G)
    const float4* __restrict__ gt_boxes,  // (B, G, 4)
    float*        __restrict__ out)       // [B*2*N maxes][B*N pos][B*N neg]
{
    __shared__ float4 s_box[GG];             // nc from front, crowd from back
    __shared__ float4 s_area4[GG / 4];
    __shared__ float  s_ncm[WAVES][RPB];
    __shared__ float  s_cm[WAVES][RPB];
    __shared__ float  s_val[RPB];
    __shared__ int    s_wn[WAVES], s_wc[WAVES];   // per-wave popcounts
    float* s_area = (float*)s_area4;

    const int b    = blockIdx.y;
    const int tid  = threadIdx.x;
    const int wave = tid >> 6;
    const int lane = tid & 63;

    // ---- issue all global loads first (overlap latency with compaction) ----
    const int nbase = blockIdx.x * RPB;
    float4 r[RPT];
    float  rs[RPT];
    #pragma unroll
    for (int i = 0; i < RPT; ++i) {
        int n = nbase + i * 64 + lane;
        r[i] = (n < NN) ? rois[b * NN + n] : make_float4(0.f, 0.f, 0.f, 0.f);
    }
    const float4 box = gt_boxes[b * GG + tid];    // one GT per thread (512 == GG)
    const int    id  = gt_ids[b * GG + tid];

    #pragma unroll
    for (int i = 0; i < RPT; ++i) {
        rs[i] = (r[i].z - r[i].x) * (r[i].w - r[i].y) + 1e-8f;
        if (wave == 0)
            s_val[i * 64 + lane] =
                ((fabsf(r[i].x) + fabsf(r[i].y) + fabsf(r[i].z) + fabsf(r[i].w)) > 0.f) ? 1.f : 0.f;
    }

    // ---- ballot compaction, atomic-free (per-wave prefix) ----
    const float asum = fabsf(box.x) + fabsf(box.y) + fabsf(box.z) + fabsf(box.w);
    const bool pn = (asum > 0.0f) && (id > 0);
    const bool pc = (asum > 0.0f) && (id < 0);
    const unsigned long long mn = __ballot(pn);
    const unsigned long long mc = __ballot(pc);
    if (lane == 0) { s_wn[wave] = __popcll(mn); s_wc[wave] = __popcll(mc); }
    __syncthreads();

    int bn = 0, bc = 0, ncnt = 0, ccnt = 0;
    #pragma unroll
    for (int w = 0; w < WAVES; ++w) {
        int pw = s_wn[w], cw = s_wc[w];
        if (w < wave) { bn += pw; bc += cw; }
        ncnt += pw; ccnt += cw;
    }
    const int lo     = GG - ccnt;
    int nc_eff = (ncnt + 3) & ~3;          // pad nc list up to x4
    int lo_pad = lo & ~3;                  // pad crowd list down to x4
    if (nc_eff > lo_pad) nc_eff = lo_pad;

    {
        const unsigned long long lt = (1ULL << lane) - 1ULL;
        if (pn) {
            int idx = bn + __popcll(mn & lt);
            s_box[idx]  = box;
            s_area[idx] = (box.z - box.x) * (box.w - box.y);
        }
        if (pc) {
            int idx = (GG - 1) - (bc + __popcll(mc & lt));
            s_box[idx]  = box;
            s_area[idx] = (box.z - box.x) * (box.w - box.y);
        }
        // zero-fill pad slots (zero box => t=0, harmless for max)
        const float4 z = make_float4(0.f, 0.f, 0.f, 0.f);
        if (tid < 4) {
            int i = ncnt + tid;
            if (i < nc_eff) { s_box[i] = z; s_area[i] = 0.f; }
        } else if (tid < 8) {
            int i = lo_pad + (tid - 4);
            if (i < lo) { s_box[i] = z; s_area[i] = 0.f; }
        }
    }
    __syncthreads();

    // t = inter * rcp(rarea + garea + eps)  (monotone in IoU; 12 VALU/pair)
    auto tval = [](const float4& rr, float rsum, const float4& g4, float ga) -> float {
        float dy = fminf(rr.z, g4.z) - fmaxf(rr.x, g4.x);
        float dx = fminf(rr.w, g4.w) - fmaxf(rr.y, g4.y);
        float inter = fmaxf(fmaxf(dy, 0.f) * dx, 0.f);
        return inter * __builtin_amdgcn_rcpf(rsum + ga);
    };

    float anc[RPT] = {0.f, 0.f, 0.f};
    float ac[RPT]  = {0.f, 0.f, 0.f};

    // Software-pipelined group loop: load group q+1 while computing group q.
    auto run = [&](int q0, int q1, float* acc) {
        if (q0 >= q1) return;
        float4 nb0 = s_box[4 * q0 + 0];
        float4 nb1 = s_box[4 * q0 + 1];
        float4 nb2 = s_box[4 * q0 + 2];
        float4 nb3 = s_box[4 * q0 + 3];
        float4 na  = s_area4[q0];
        #pragma unroll 2
        for (int q = q0; q < q1; ++q) {
            const float4 cb0 = nb0, cb1 = nb1, cb2 = nb2, cb3 = nb3, ca = na;
            const int qn = (q + 1 < q1) ? q + 1 : q0;     // wrap: last prefetch unused
            nb0 = s_box[4 * qn + 0];
            nb1 = s_box[4 * qn + 1];
            nb2 = s_box[4 * qn + 2];
            nb3 = s_box[4 * qn + 3];
            na  = s_area4[qn];
            #pragma unroll
            for (int i = 0; i < RPT; ++i) {
                float t0 = tval(r[i], rs[i], cb0, ca.x);
                float t1 = tval(r[i], rs[i], cb1, ca.y);
                float t2 = tval(r[i], rs[i], cb2, ca.z);
                float t3 = tval(r[i], rs[i], cb3, ca.w);
                acc[i] = fmaxf(acc[i], fmaxf(fmaxf(t0, t1), fmaxf(t2, t3)));
            }
        }
    };

    // ---- non-crowd: groups [0, nc_eff/4), split across 8 waves ----
    {
        const int ngr = nc_eff >> 2;
        const int gpw = (ngr + WAVES - 1) / WAVES;
        const int q0 = __builtin_amdgcn_readfirstlane(wave * gpw);
        const int q1 = __builtin_amdgcn_readfirstlane(min(ngr, q0 + gpw));
        run(q0, q1, anc);
    }
    // ---- crowd: groups [lo_pad/4, GG/4), split across 8 waves ----
    {
        const int cg0 = lo_pad >> 2;
        const int cgn = (GG >> 2) - cg0;
        const int gpw = (cgn + WAVES - 1) / WAVES;
        const int q0 = __builtin_amdgcn_readfirstlane(cg0 + wave * gpw);
        const int q1 = __builtin_amdgcn_readfirstlane(min(GG >> 2, q0 + gpw));
        run(q0, q1, ac);
    }

    #pragma unroll
    for (int i = 0; i < RPT; ++i) {
        s_ncm[wave][i * 64 + lane] = anc[i];
        s_cm[wave][i * 64 + lane]  = ac[i];
    }
    __syncthreads();

    // ---- reduce across waves; threads 0..RPB-1 own one ROI slot each ----
    if (tid < RPB) {
        const int n = nbase + tid;
        if (n < NN) {
            float a = s_ncm[0][tid], c = s_cm[0][tid];
            #pragma unroll
            for (int w = 1; w < WAVES; ++w) {
                a = fmaxf(a, s_ncm[w][tid]);
                c = fmaxf(c, s_cm[w][tid]);
            }
            const float vr = s_val[tid];           // 1.0 or 0.0
            a *= vr;
            c *= vr;
            // t -> iou: iou = t/(1-t); t in [0, 0.5] so well-conditioned
            const float nc_max = a * __builtin_amdgcn_rcpf(1.f - a);
            const float c_max  = c * __builtin_amdgcn_rcpf(1.f - c);

            out[b * 2 * NN + n]      = nc_max;     // iou_maxes (B,2,N) ch0
            out[b * 2 * NN + NN + n] = c_max;      // iou_maxes (B,2,N) ch1
            const float pos = (vr > 0.f && nc_max >= 0.5f) ? 1.0f : 0.0f;
            const float neg = (vr > 0.f && nc_max < 0.5f && c_max < 0.001f) ? 1.0f : 0.0f;
            out[BB * 2 * NN + b * NN + n]           = pos;
            out[BB * 2 * NN + BB * NN + b * NN + n] = neg;
        }
    }
}

extern "C" void kernel_launch(void* const* d_in, const int* in_sizes, int n_in,
                              void* d_out, int out_size, void* d_ws, size_t ws_size,
                              hipStream_t stream) {
    const float4* rois     = (const float4*)d_in[0];
    const int*    gt_ids   = (const int*)d_in[1];
    const float4* gt_boxes = (const float4*)d_in[2];
    float*        out      = (float*)d_out;

    dim3 grid((NN + RPB - 1) / RPB, BB);   // 32 x 16 = 512 blocks = exactly 2/CU
    det_kernel<<<grid, 64 * WAVES, 0, stream>>>(rois, gt_ids, gt_boxes, out);
}